// Round 5
// baseline (78.876 us; speedup 1.0000x reference)
//
#include <hip/hip_runtime.h>

#define OUT_N 5
#define TOTAL_NODES 65024
#define ROOTS_OFF (TOTAL_NODES * OUT_N)
#define NLEAF 32768

typedef __attribute__((ext_vector_type(8))) short bf16x8;
typedef __attribute__((ext_vector_type(4))) float f32x4;
typedef __attribute__((ext_vector_type(8))) unsigned short ushort8v;
typedef __attribute__((ext_vector_type(4))) unsigned int uint4v;

static __device__ __forceinline__ float bf2f(unsigned short u) {
    union { unsigned int i; float f; } v; v.i = ((unsigned int)u) << 16; return v.f;
}
static __device__ __forceinline__ unsigned short f2bf(float f) {
    union { float f; unsigned int i; } v; v.f = f;
    unsigned int r = v.i + 0x7fff + ((v.i >> 16) & 1);   // RNE
    return (unsigned short)(r >> 16);
}
// node row R, 16B chunk q: XOR-swizzled byte offset (breaks 16-way conflicts)
static __device__ __forceinline__ int node_addr(int R, int q) {
    return R * 64 + (((q ^ ((R >> 1) & 3)) & 3) << 4);
}

// ---------------------------------------------------------------------------
// bprep: symmetric-pair B table (K=2144 -> 67 ksteps), MFMA-fragment order.
// ---------------------------------------------------------------------------
__global__ __launch_bounds__(256) void bprep_kernel(
    const float* __restrict__ V, const float* __restrict__ W,
    unsigned short* __restrict__ B)
{
    int t = blockIdx.x * 256 + threadIdx.x;
    if (t >= 8576) return;                   // 67*2*64
    int ks = t >> 7, sub = t & 127;
    int n = sub >> 6, lane = sub & 63;
    int hi = lane >> 4, l15 = lane & 15;
    int k = n * 16 + l15;
    const float* Vk = V + (size_t)k * 4096;
    ushort8v o;
    #pragma unroll
    for (int i = 0; i < 8; ++i) {
        int r5 = hi * 8 + i;
        float val;
        if (ks < 2)        { int j = 32 * ks + r5; val = Vk[j * 64 + j]; }
        else if (ks < 64)  { int d = ks >> 1; int j = 32 * (ks & 1) + r5; int l = (j + d) & 63;
                             val = Vk[j * 64 + l] + Vk[l * 64 + j]; }
        else if (ks == 64) { int j = r5; val = Vk[j * 64 + j + 32] + Vk[(j + 32) * 64 + j]; }
        else               { int j = (ks == 65) ? r5 : (32 + r5); val = W[j * 32 + k]; }
        o[i] = f2bf(val);
    }
    *(ushort8v*)(B + (size_t)t * 8) = o;
}

// ---------------------------------------------------------------------------
// crot[x] = c[(x + hi*8) & 63] loaded from swizzled LDS node rows (Rc, Rc+1)
// ---------------------------------------------------------------------------
static __device__ __forceinline__ void load_crot(
    const char* nodes, int Rc, int hi, float* crot)
{
    #pragma unroll
    for (int t = 0; t < 8; ++t) {
        int m = (hi + t) & 7;
        ushort8v v = *(const ushort8v*)(nodes + node_addr(Rc + (m >> 2), m & 3));
        #pragma unroll
        for (int e = 0; e < 8; ++e) crot[t * 8 + e] = bf2f(v[e]);
    }
}

// ---------------------------------------------------------------------------
// One wave's k-range of the symmetric outer-product GEMM, single ntile n.
// All crot indices compile-time (rotation trick). B from GLOBAL (L2-broadcast).
// ---------------------------------------------------------------------------
static __device__ __forceinline__ f32x4 run_k(
    const unsigned short* __restrict__ Bg, const float* crot,
    int lane, int n, int k0, int k1, f32x4 acc)
{
    const char* bp = (const char*)Bg + lane * 16;
    #pragma unroll
    for (int ks = 0; ks < 67; ++ks) {
        if (ks >= k0 && ks < k1) {            // wave-uniform scalar guard
            uint4v aw;
            #pragma unroll
            for (int q = 0; q < 4; ++q) {
                int i0 = 2 * q, i1 = 2 * q + 1;
                float p0, p1;
                if (ks < 2)       { p0 = crot[32*ks+i0] * crot[32*ks+i0];
                                    p1 = crot[32*ks+i1] * crot[32*ks+i1]; }
                else if (ks < 64) { const int bse = 32 * (ks & 1), d = ks >> 1;
                                    p0 = crot[bse+i0] * crot[(bse+i0+d)&63];
                                    p1 = crot[bse+i1] * crot[(bse+i1+d)&63]; }
                else if (ks == 64){ p0 = crot[i0] * crot[32+i0];
                                    p1 = crot[i1] * crot[32+i1]; }
                else if (ks == 65){ p0 = crot[i0];    p1 = crot[i1]; }
                else              { p0 = crot[32+i0]; p1 = crot[32+i1]; }
                unsigned int pk;
                asm("v_cvt_pk_bf16_f32 %0, %1, %2" : "=v"(pk) : "v"(p0), "v"(p1));
                aw[q] = pk;
            }
            bf16x8 afr = __builtin_bit_cast(bf16x8, aw);
            bf16x8 bfr = *(const bf16x8*)(bp + ((ks * 2 + n) << 10));
            acc = __builtin_amdgcn_mfma_f32_16x16x32_bf16(afr, bfr, acc, 0, 0, 0);
        }
    }
    return acc;
}

// ---------------------------------------------------------------------------
// L1 kernel: fused embed gather + level 1. Block = one 16-row M-tile,
// 4 waves = splitN2 x splitK2. 1024 blocks -> 4 blocks/CU, 4 waves/SIMD.
// ---------------------------------------------------------------------------
__global__ __launch_bounds__(256, 4) void l1_kernel(
    const int* __restrict__ word_ids, const float* __restrict__ embed,
    const unsigned short* __restrict__ Bg, const float* __restrict__ bias,
    unsigned short* __restrict__ h1)
{
    __shared__ char smem[2048 + 2048];       // 32 node rows | 2 splitK slots
    const int tid = threadIdx.x, lane = tid & 63;
    const int l15 = lane & 15, hi = lane >> 4, wave = tid >> 6;
    const int n = wave >> 1, u = wave & 1;
    const int tile = blockIdx.x;

    // stage 32 leaf rows (bf16, swizzled). 256 thr x 8B.
    {
        int rr = tid >> 3, q4 = tid & 7;
        int r = rr >> 1, child = rr & 1;
        int g1 = tile * 16 + r;
        int leaf = (g1 >> 5) * 64 + (g1 & 31) * 2 + child;
        int wid = word_ids[leaf];
        float4 v = ((const float4*)(embed + (size_t)wid * 32))[q4];
        uint2 st;
        st.x = (unsigned)f2bf(v.x) | ((unsigned)f2bf(v.y) << 16);
        st.y = (unsigned)f2bf(v.z) | ((unsigned)f2bf(v.w) << 16);
        *(uint2*)(smem + node_addr(rr, q4 >> 1) + (q4 & 1) * 8) = st;
    }
    __syncthreads();

    float crot[64];
    load_crot(smem, 2 * l15, hi, crot);

    f32x4 acc = { 0.f, 0.f, 0.f, 0.f };
    acc = run_k(Bg, crot, lane, n, u ? 34 : 0, u ? 67 : 34, acc);

    if (u == 1) *(f32x4*)(smem + 2048 + n * 1024 + lane * 16) = acc;
    __syncthreads();
    if (u == 0) {
        acc += *(const f32x4*)(smem + 2048 + n * 1024 + lane * 16);
        float bk = bias[n * 16 + l15];
        #pragma unroll
        for (int r = 0; r < 4; ++r) {
            int node = tile * 16 + hi * 4 + r;
            h1[(size_t)node * 32 + n * 16 + l15] = f2bf(tanhf(acc[r] + bk));
        }
    }
}

// ---------------------------------------------------------------------------
// Tail kernel: levels 2..6, block = one tree, 8 waves = splitN2 x splitK4.
// LDS node rows: 0..31 h1(in), 32..47 L2, 48..55 L3, 56..59 L4, 60..61 L5, 62 L6.
// ---------------------------------------------------------------------------
__global__ __launch_bounds__(512, 4) void tail_kernel(
    const unsigned short* __restrict__ Bg, const float* __restrict__ bias,
    unsigned short* __restrict__ hbuf, float* __restrict__ roots)
{
    __shared__ char smem[4096 + 6144];       // 63 node rows | 6 splitK slots
    const int tid = threadIdx.x, lane = tid & 63;
    const int l15 = lane & 15, hi = lane >> 4, wave = tid >> 6;
    const int n = wave >> 2, u = wave & 3;
    const int tree = blockIdx.x;

    // stage this tree's 32 h1 nodes (2 KB) coalesced
    {
        int e2 = tid * 2;
        int i = e2 >> 5, col = e2 & 31;
        unsigned int v = *(const unsigned int*)(hbuf + ((size_t)tree * 32 + i) * 32 + col);
        *(unsigned int*)(smem + node_addr(i, col >> 3) + (col & 7) * 2) = v;
    }
    __syncthreads();

    const int k0 = (u == 0) ? 0 : (u == 1) ? 17 : (u == 2) ? 34 : 50;
    const int k1 = (u == 0) ? 17 : (u == 1) ? 34 : (u == 2) ? 50 : 67;

    for (int L = 2; L <= 6; ++L) {
        const int nOut = 32 >> (L - 1);                       // 16,8,4,2,1
        const int inb  = (L==2)?0:(L==3)?32:(L==4)?48:(L==5)?56:60;
        const int outb = (L==2)?32:(L==3)?48:(L==4)?56:(L==5)?60:62;
        const int Og   = (L==2)?16384:(L==3)?24576:(L==4)?28672:(L==5)?30720:31744;

        int rowc = (l15 < nOut) ? l15 : 0;
        float crot[64];
        load_crot(smem, inb + 2 * rowc, hi, crot);

        f32x4 acc = { 0.f, 0.f, 0.f, 0.f };
        acc = run_k(Bg, crot, lane, n, k0, k1, acc);

        if (u > 0) *(f32x4*)(smem + 4096 + (n * 3 + u - 1) * 1024 + lane * 16) = acc;
        __syncthreads();
        if (u == 0) {
            #pragma unroll
            for (int v2 = 0; v2 < 3; ++v2)
                acc += *(const f32x4*)(smem + 4096 + (n * 3 + v2) * 1024 + lane * 16);
            float bk = bias[n * 16 + l15];
            int col = n * 16 + l15;
            #pragma unroll
            for (int r = 0; r < 4; ++r) {
                int row = hi * 4 + r;
                if (row < nOut) {
                    float h = tanhf(acc[r] + bk);
                    unsigned short hb = f2bf(h);
                    *(unsigned short*)(smem + node_addr(outb + row, col >> 3) + (col & 7) * 2) = hb;
                    hbuf[((size_t)Og + (size_t)tree * nOut + row) * 32 + col] = hb;
                    if (L == 6) roots[(size_t)tree * 32 + col] = h;
                }
            }
        }
        __syncthreads();
    }
}

// ---------------------------------------------------------------------------
// out: logits + log_softmax. Leaves straight from fp32 embed (no leaf buffer).
// ---------------------------------------------------------------------------
__global__ __launch_bounds__(256) void out_kernel(
    const int* __restrict__ word_ids, const float* __restrict__ embed,
    const unsigned short* __restrict__ hbuf,
    const float* __restrict__ Wout_w, const float* __restrict__ Wout_b,
    float* __restrict__ out)
{
    int g = blockIdx.x * 256 + threadIdx.x;
    if (g >= TOTAL_NODES) return;

    float h[32];
    if (g < NLEAF) {
        int wid = word_ids[g];
        const float4* p = (const float4*)(embed + (size_t)wid * 32);
        #pragma unroll
        for (int q = 0; q < 8; ++q) {
            float4 v = p[q];
            h[q*4] = v.x; h[q*4+1] = v.y; h[q*4+2] = v.z; h[q*4+3] = v.w;
        }
    } else {
        const ushort8v* p = (const ushort8v*)(hbuf + (size_t)(g - NLEAF) * 32);
        #pragma unroll
        for (int q = 0; q < 4; ++q) {
            ushort8v v = p[q];
            #pragma unroll
            for (int e = 0; e < 8; ++e) h[q*8+e] = bf2f(v[e]);
        }
    }

    float logits[OUT_N];
    #pragma unroll
    for (int o = 0; o < OUT_N; ++o) {
        const float* w = Wout_w + o * 32;
        float s = 0.f;
        #pragma unroll
        for (int x = 0; x < 32; ++x) s = fmaf(w[x], h[x], s);
        logits[o] = s + Wout_b[o];
    }
    float m = logits[0];
    #pragma unroll
    for (int o = 1; o < OUT_N; ++o) m = fmaxf(m, logits[o]);
    float sum = 0.f;
    #pragma unroll
    for (int o = 0; o < OUT_N; ++o) sum += expf(logits[o] - m);
    float lse = m + logf(sum);
    #pragma unroll
    for (int o = 0; o < OUT_N; ++o) out[(size_t)g * OUT_N + o] = logits[o] - lse;
}

// ---------------------------------------------------------------------------
extern "C" void kernel_launch(void* const* d_in, const int* in_sizes, int n_in,
                              void* d_out, int out_size, void* d_ws, size_t ws_size,
                              hipStream_t stream)
{
    const int*   word_ids = (const int*)  d_in[0];
    const float* embed    = (const float*)d_in[1];
    const float* V        = (const float*)d_in[2];
    const float* W        = (const float*)d_in[3];
    const float* bvec     = (const float*)d_in[4];
    const float* Wout_w   = (const float*)d_in[5];
    const float* Wout_b   = (const float*)d_in[6];
    float* out = (float*)d_out;

    // ws: Bfrag [137216 B] | hbuf 32256 nodes x 32 bf16 [2,064,384 B]
    unsigned short* Bfrag = (unsigned short*)d_ws;
    unsigned short* hbuf  = (unsigned short*)((char*)d_ws + 137216);
    float* roots = out + ROOTS_OFF;

    bprep_kernel<<<34, 256, 0, stream>>>(V, W, Bfrag);
    l1_kernel<<<1024, 256, 0, stream>>>(word_ids, embed, Bfrag, bvec, hbuf);
    tail_kernel<<<512, 512, 0, stream>>>(Bfrag, bvec, hbuf, roots);
    out_kernel<<<254, 256, 0, stream>>>(word_ids, embed, hbuf, Wout_w, Wout_b, out);
}

// Round 6
// 62.739 us; speedup vs baseline: 1.2572x; 1.2572x over previous
//
#include <hip/hip_runtime.h>

#define OUT_N 5
#define TOTAL_NODES 65024
#define ROOTS_OFF (TOTAL_NODES * OUT_N)
#define NLEAF 32768

typedef __attribute__((ext_vector_type(8))) short bf16x8;
typedef __attribute__((ext_vector_type(4))) float f32x4;
typedef __attribute__((ext_vector_type(8))) unsigned short ushort8v;
typedef __attribute__((ext_vector_type(4))) unsigned int uint4v;

static __device__ __forceinline__ float bf2f(unsigned short u) {
    union { unsigned int i; float f; } v; v.i = ((unsigned int)u) << 16; return v.f;
}
static __device__ __forceinline__ unsigned short f2bf(float f) {
    union { float f; unsigned int i; } v; v.f = f;
    unsigned int r = v.i + 0x7fff + ((v.i >> 16) & 1);   // RNE
    return (unsigned short)(r >> 16);
}
// node row R, 16B chunk q: XOR-swizzled byte offset (breaks 16-way conflicts)
static __device__ __forceinline__ int node_addr(int R, int q) {
    return R * 64 + (((q ^ ((R >> 1) & 3)) & 3) << 4);
}

// ---------------------------------------------------------------------------
// bprep: symmetric-pair B table (K=2144 -> 67 ksteps), MFMA-fragment order.
// ---------------------------------------------------------------------------
__global__ __launch_bounds__(256) void bprep_kernel(
    const float* __restrict__ V, const float* __restrict__ W,
    unsigned short* __restrict__ B)
{
    int t = blockIdx.x * 256 + threadIdx.x;
    if (t >= 8576) return;                   // 67*2*64
    int ks = t >> 7, sub = t & 127;
    int n = sub >> 6, lane = sub & 63;
    int hi = lane >> 4, l15 = lane & 15;
    int k = n * 16 + l15;
    const float* Vk = V + (size_t)k * 4096;
    ushort8v o;
    #pragma unroll
    for (int i = 0; i < 8; ++i) {
        int r5 = hi * 8 + i;
        float val;
        if (ks < 2)        { int j = 32 * ks + r5; val = Vk[j * 64 + j]; }
        else if (ks < 64)  { int d = ks >> 1; int j = 32 * (ks & 1) + r5; int l = (j + d) & 63;
                             val = Vk[j * 64 + l] + Vk[l * 64 + j]; }
        else if (ks == 64) { int j = r5; val = Vk[j * 64 + j + 32] + Vk[(j + 32) * 64 + j]; }
        else               { int j = (ks == 65) ? r5 : (32 + r5); val = W[j * 32 + k]; }
        o[i] = f2bf(val);
    }
    *(ushort8v*)(B + (size_t)t * 8) = o;
}

// ---------------------------------------------------------------------------
// crot[x] = c[(x + hi*8) & 63] loaded from swizzled LDS node rows (Rc, Rc+1)
// ---------------------------------------------------------------------------
static __device__ __forceinline__ void load_crot(
    const char* nodes, int Rc, int hi, float* crot)
{
    #pragma unroll
    for (int t = 0; t < 8; ++t) {
        int m = (hi + t) & 7;
        ushort8v v = *(const ushort8v*)(nodes + node_addr(Rc + (m >> 2), m & 3));
        #pragma unroll
        for (int e = 0; e < 8; ++e) crot[t * 8 + e] = bf2f(v[e]);
    }
}

// ---------------------------------------------------------------------------
// One wave's k-range of the symmetric outer-product GEMM, single ntile n.
// All crot indices compile-time (rotation trick). B from GLOBAL (L2-broadcast).
// ---------------------------------------------------------------------------
static __device__ __forceinline__ f32x4 run_k(
    const unsigned short* __restrict__ Bg, const float* crot,
    int lane, int n, int k0, int k1, f32x4 acc)
{
    const char* bp = (const char*)Bg + lane * 16;
    #pragma unroll
    for (int ks = 0; ks < 67; ++ks) {
        if (ks >= k0 && ks < k1) {            // wave-uniform scalar guard
            uint4v aw;
            #pragma unroll
            for (int q = 0; q < 4; ++q) {
                int i0 = 2 * q, i1 = 2 * q + 1;
                float p0, p1;
                if (ks < 2)       { p0 = crot[32*ks+i0] * crot[32*ks+i0];
                                    p1 = crot[32*ks+i1] * crot[32*ks+i1]; }
                else if (ks < 64) { const int bse = 32 * (ks & 1), d = ks >> 1;
                                    p0 = crot[bse+i0] * crot[(bse+i0+d)&63];
                                    p1 = crot[bse+i1] * crot[(bse+i1+d)&63]; }
                else if (ks == 64){ p0 = crot[i0] * crot[32+i0];
                                    p1 = crot[i1] * crot[32+i1]; }
                else if (ks == 65){ p0 = crot[i0];    p1 = crot[i1]; }
                else              { p0 = crot[32+i0]; p1 = crot[32+i1]; }
                unsigned int pk;
                asm("v_cvt_pk_bf16_f32 %0, %1, %2" : "=v"(pk) : "v"(p0), "v"(p1));
                aw[q] = pk;
            }
            bf16x8 afr = __builtin_bit_cast(bf16x8, aw);
            bf16x8 bfr = *(const bf16x8*)(bp + ((ks * 2 + n) << 10));
            acc = __builtin_amdgcn_mfma_f32_16x16x32_bf16(afr, bfr, acc, 0, 0, 0);
        }
    }
    return acc;
}

// ---------------------------------------------------------------------------
// L1 kernel: fused embed gather + level 1. Block = one 16-row M-tile,
// 4 waves = splitN2 x splitK2. 1024 blocks; cap 128 VGPR (needs ~88, fits).
// ---------------------------------------------------------------------------
__global__ __launch_bounds__(256, 4) void l1_kernel(
    const int* __restrict__ word_ids, const float* __restrict__ embed,
    const unsigned short* __restrict__ Bg, const float* __restrict__ bias,
    unsigned short* __restrict__ h1)
{
    __shared__ char smem[2048 + 2048];       // 32 node rows | 2 splitK slots
    const int tid = threadIdx.x, lane = tid & 63;
    const int l15 = lane & 15, hi = lane >> 4, wave = tid >> 6;
    const int n = wave >> 1, u = wave & 1;
    const int tile = blockIdx.x;

    // stage 32 leaf rows (bf16, swizzled). 256 thr x 8B.
    {
        int rr = tid >> 3, q4 = tid & 7;
        int r = rr >> 1, child = rr & 1;
        int g1 = tile * 16 + r;
        int leaf = (g1 >> 5) * 64 + (g1 & 31) * 2 + child;
        int wid = word_ids[leaf];
        float4 v = ((const float4*)(embed + (size_t)wid * 32))[q4];
        uint2 st;
        st.x = (unsigned)f2bf(v.x) | ((unsigned)f2bf(v.y) << 16);
        st.y = (unsigned)f2bf(v.z) | ((unsigned)f2bf(v.w) << 16);
        *(uint2*)(smem + node_addr(rr, q4 >> 1) + (q4 & 1) * 8) = st;
    }
    __syncthreads();

    float crot[64];
    load_crot(smem, 2 * l15, hi, crot);

    f32x4 acc = { 0.f, 0.f, 0.f, 0.f };
    acc = run_k(Bg, crot, lane, n, u ? 34 : 0, u ? 67 : 34, acc);

    if (u == 1) *(f32x4*)(smem + 2048 + n * 1024 + lane * 16) = acc;
    __syncthreads();
    if (u == 0) {
        acc += *(const f32x4*)(smem + 2048 + n * 1024 + lane * 16);
        float bk = bias[n * 16 + l15];
        #pragma unroll
        for (int r = 0; r < 4; ++r) {
            int node = tile * 16 + hi * 4 + r;
            h1[(size_t)node * 32 + n * 16 + l15] = f2bf(tanhf(acc[r] + bk));
        }
    }
}

// ---------------------------------------------------------------------------
// Tail kernel: levels 2..6, block = one tree, 8 waves = splitN2 x splitK4.
// __launch_bounds__(512, 2): cap 128 VGPR (needs ~88) — (512,4) capped at 64
// and spilled crot[] to scratch = 95 MB HBM writes (round-5 regression).
// LDS node rows: 0..31 h1(in), 32..47 L2, 48..55 L3, 56..59 L4, 60..61 L5, 62 L6.
// ---------------------------------------------------------------------------
__global__ __launch_bounds__(512, 2) void tail_kernel(
    const unsigned short* __restrict__ Bg, const float* __restrict__ bias,
    unsigned short* __restrict__ hbuf, float* __restrict__ roots)
{
    __shared__ char smem[4096 + 6144];       // 63 node rows | 6 splitK slots
    const int tid = threadIdx.x, lane = tid & 63;
    const int l15 = lane & 15, hi = lane >> 4, wave = tid >> 6;
    const int n = wave >> 2, u = wave & 3;
    const int tree = blockIdx.x;

    // stage this tree's 32 h1 nodes (2 KB) coalesced
    {
        int e2 = tid * 2;
        int i = e2 >> 5, col = e2 & 31;
        unsigned int v = *(const unsigned int*)(hbuf + ((size_t)tree * 32 + i) * 32 + col);
        *(unsigned int*)(smem + node_addr(i, col >> 3) + (col & 7) * 2) = v;
    }
    __syncthreads();

    const int k0 = (u == 0) ? 0 : (u == 1) ? 17 : (u == 2) ? 34 : 50;
    const int k1 = (u == 0) ? 17 : (u == 1) ? 34 : (u == 2) ? 50 : 67;

    for (int L = 2; L <= 6; ++L) {
        const int nOut = 32 >> (L - 1);                       // 16,8,4,2,1
        const int inb  = (L==2)?0:(L==3)?32:(L==4)?48:(L==5)?56:60;
        const int outb = (L==2)?32:(L==3)?48:(L==4)?56:(L==5)?60:62;
        const int Og   = (L==2)?16384:(L==3)?24576:(L==4)?28672:(L==5)?30720:31744;

        int rowc = (l15 < nOut) ? l15 : 0;
        float crot[64];
        load_crot(smem, inb + 2 * rowc, hi, crot);

        f32x4 acc = { 0.f, 0.f, 0.f, 0.f };
        acc = run_k(Bg, crot, lane, n, k0, k1, acc);

        if (u > 0) *(f32x4*)(smem + 4096 + (n * 3 + u - 1) * 1024 + lane * 16) = acc;
        __syncthreads();
        if (u == 0) {
            #pragma unroll
            for (int v2 = 0; v2 < 3; ++v2)
                acc += *(const f32x4*)(smem + 4096 + (n * 3 + v2) * 1024 + lane * 16);
            float bk = bias[n * 16 + l15];
            int col = n * 16 + l15;
            #pragma unroll
            for (int r = 0; r < 4; ++r) {
                int row = hi * 4 + r;
                if (row < nOut) {
                    float h = tanhf(acc[r] + bk);
                    unsigned short hb = f2bf(h);
                    *(unsigned short*)(smem + node_addr(outb + row, col >> 3) + (col & 7) * 2) = hb;
                    hbuf[((size_t)Og + (size_t)tree * nOut + row) * 32 + col] = hb;
                    if (L == 6) roots[(size_t)tree * 32 + col] = h;
                }
            }
        }
        __syncthreads();
    }
}

// ---------------------------------------------------------------------------
// out: logits + log_softmax. Leaves straight from fp32 embed (no leaf buffer).
// ---------------------------------------------------------------------------
__global__ __launch_bounds__(256) void out_kernel(
    const int* __restrict__ word_ids, const float* __restrict__ embed,
    const unsigned short* __restrict__ hbuf,
    const float* __restrict__ Wout_w, const float* __restrict__ Wout_b,
    float* __restrict__ out)
{
    int g = blockIdx.x * 256 + threadIdx.x;
    if (g >= TOTAL_NODES) return;

    float h[32];
    if (g < NLEAF) {
        int wid = word_ids[g];
        const float4* p = (const float4*)(embed + (size_t)wid * 32);
        #pragma unroll
        for (int q = 0; q < 8; ++q) {
            float4 v = p[q];
            h[q*4] = v.x; h[q*4+1] = v.y; h[q*4+2] = v.z; h[q*4+3] = v.w;
        }
    } else {
        const ushort8v* p = (const ushort8v*)(hbuf + (size_t)(g - NLEAF) * 32);
        #pragma unroll
        for (int q = 0; q < 4; ++q) {
            ushort8v v = p[q];
            #pragma unroll
            for (int e = 0; e < 8; ++e) h[q*8+e] = bf2f(v[e]);
        }
    }

    float logits[OUT_N];
    #pragma unroll
    for (int o = 0; o < OUT_N; ++o) {
        const float* w = Wout_w + o * 32;
        float s = 0.f;
        #pragma unroll
        for (int x = 0; x < 32; ++x) s = fmaf(w[x], h[x], s);
        logits[o] = s + Wout_b[o];
    }
    float m = logits[0];
    #pragma unroll
    for (int o = 1; o < OUT_N; ++o) m = fmaxf(m, logits[o]);
    float sum = 0.f;
    #pragma unroll
    for (int o = 0; o < OUT_N; ++o) sum += expf(logits[o] - m);
    float lse = m + logf(sum);
    #pragma unroll
    for (int o = 0; o < OUT_N; ++o) out[(size_t)g * OUT_N + o] = logits[o] - lse;
}

// ---------------------------------------------------------------------------
extern "C" void kernel_launch(void* const* d_in, const int* in_sizes, int n_in,
                              void* d_out, int out_size, void* d_ws, size_t ws_size,
                              hipStream_t stream)
{
    const int*   word_ids = (const int*)  d_in[0];
    const float* embed    = (const float*)d_in[1];
    const float* V        = (const float*)d_in[2];
    const float* W        = (const float*)d_in[3];
    const float* bvec     = (const float*)d_in[4];
    const float* Wout_w   = (const float*)d_in[5];
    const float* Wout_b   = (const float*)d_in[6];
    float* out = (float*)d_out;

    // ws: Bfrag [137216 B] | hbuf 32256 nodes x 32 bf16 [2,064,384 B]
    unsigned short* Bfrag = (unsigned short*)d_ws;
    unsigned short* hbuf  = (unsigned short*)((char*)d_ws + 137216);
    float* roots = out + ROOTS_OFF;

    bprep_kernel<<<34, 256, 0, stream>>>(V, W, Bfrag);
    l1_kernel<<<1024, 256, 0, stream>>>(word_ids, embed, Bfrag, bvec, hbuf);
    tail_kernel<<<512, 512, 0, stream>>>(Bfrag, bvec, hbuf, roots);
    out_kernel<<<254, 256, 0, stream>>>(word_ids, embed, hbuf, Wout_w, Wout_b, out);
}

// Round 7
// 34.513 us; speedup vs baseline: 2.2854x; 1.8178x over previous
//
#include <hip/hip_runtime.h>

#define OUT_N 5
#define TOTAL_NODES 65024
#define ROOTS_OFF (TOTAL_NODES * OUT_N)
#define NLEAF 32768

typedef __attribute__((ext_vector_type(8))) short bf16x8;
typedef __attribute__((ext_vector_type(4))) float f32x4;
typedef __attribute__((ext_vector_type(8))) unsigned short ushort8v;
typedef __attribute__((ext_vector_type(4))) unsigned int uint4v;

static __device__ __forceinline__ float bf2f(unsigned short u) {
    union { unsigned int i; float f; } v; v.i = ((unsigned int)u) << 16; return v.f;
}
static __device__ __forceinline__ unsigned short f2bf(float f) {
    union { float f; unsigned int i; } v; v.f = f;
    unsigned int r = v.i + 0x7fff + ((v.i >> 16) & 1);   // RNE
    return (unsigned short)(r >> 16);
}
// node row R, 16B chunk q: XOR-swizzled byte offset (breaks 16-way conflicts)
static __device__ __forceinline__ int node_addr(int R, int q) {
    return R * 64 + (((q ^ ((R >> 1) & 3)) & 3) << 4);
}

// ---------------------------------------------------------------------------
// bprep: symmetric-pair B table (K=2144 -> 67 ksteps), MFMA-fragment order.
// 134 single-wave blocks (latency-bound gather -> spread over CUs).
// ---------------------------------------------------------------------------
__global__ __launch_bounds__(64) void bprep_kernel(
    const float* __restrict__ V, const float* __restrict__ W,
    unsigned short* __restrict__ B)
{
    int t = blockIdx.x * 64 + threadIdx.x;
    if (t >= 8576) return;                   // 67*2*64
    int ks = t >> 7, sub = t & 127;
    int n = sub >> 6, lane = sub & 63;
    int hi = lane >> 4, l15 = lane & 15;
    int k = n * 16 + l15;
    const float* Vk = V + (size_t)k * 4096;
    ushort8v o;
    #pragma unroll
    for (int i = 0; i < 8; ++i) {
        int r5 = hi * 8 + i;
        float val;
        if (ks < 2)        { int j = 32 * ks + r5; val = Vk[j * 64 + j]; }
        else if (ks < 64)  { int d = ks >> 1; int j = 32 * (ks & 1) + r5; int l = (j + d) & 63;
                             val = Vk[j * 64 + l] + Vk[l * 64 + j]; }
        else if (ks == 64) { int j = r5; val = Vk[j * 64 + j + 32] + Vk[(j + 32) * 64 + j]; }
        else               { int j = (ks == 65) ? r5 : (32 + r5); val = W[j * 32 + k]; }
        o[i] = f2bf(val);
    }
    *(ushort8v*)(B + (size_t)t * 8) = o;
}

// ---------------------------------------------------------------------------
// crot[x] = c[(x + hi*8) & 63] loaded from swizzled LDS node rows (Rc, Rc+1)
// ---------------------------------------------------------------------------
static __device__ __forceinline__ void load_crot(
    const char* nodes, int Rc, int hi, float* crot)
{
    #pragma unroll
    for (int t = 0; t < 8; ++t) {
        int m = (hi + t) & 7;
        ushort8v v = *(const ushort8v*)(nodes + node_addr(Rc + (m >> 2), m & 3));
        #pragma unroll
        for (int e = 0; e < 8; ++e) crot[t * 8 + e] = bf2f(v[e]);
    }
}

// ---------------------------------------------------------------------------
// COMPILE-TIME k-range [K0,K1) of the symmetric outer-product GEMM, ntile n.
// (round-6 lesson: runtime-guarded 67-step unroll emits/executes dead bodies)
// ---------------------------------------------------------------------------
template<int K0, int K1>
static __device__ __forceinline__ f32x4 run1_k(
    const unsigned short* __restrict__ Bg, const float* crot,
    int lane, int n, f32x4 acc)
{
    const char* bp = (const char*)Bg + lane * 16 + (n << 10);
    #pragma unroll
    for (int ks = K0; ks < K1; ++ks) {
        uint4v aw;
        #pragma unroll
        for (int q = 0; q < 4; ++q) {
            int i0 = 2 * q, i1 = 2 * q + 1;
            float p0, p1;
            if (ks < 2)       { p0 = crot[32*ks+i0] * crot[32*ks+i0];
                                p1 = crot[32*ks+i1] * crot[32*ks+i1]; }
            else if (ks < 64) { const int bse = 32 * (ks & 1), d = ks >> 1;
                                p0 = crot[bse+i0] * crot[(bse+i0+d)&63];
                                p1 = crot[bse+i1] * crot[(bse+i1+d)&63]; }
            else if (ks == 64){ p0 = crot[i0] * crot[32+i0];
                                p1 = crot[i1] * crot[32+i1]; }
            else if (ks == 65){ p0 = crot[i0];    p1 = crot[i1]; }
            else              { p0 = crot[32+i0]; p1 = crot[32+i1]; }
            unsigned int pk;
            asm("v_cvt_pk_bf16_f32 %0, %1, %2" : "=v"(pk) : "v"(p0), "v"(p1));
            aw[q] = pk;
        }
        bf16x8 afr = __builtin_bit_cast(bf16x8, aw);
        bf16x8 bfr = *(const bf16x8*)(bp + (ks << 11));
        acc = __builtin_amdgcn_mfma_f32_16x16x32_bf16(afr, bfr, acc, 0, 0, 0);
    }
    return acc;
}

// ---------------------------------------------------------------------------
// L1 kernel: fused embed gather + level 1. Block = one 16-row M-tile,
// 4 waves = splitN2 x splitK2 (compile-time ranges). 1024 blocks.
// ---------------------------------------------------------------------------
__global__ __launch_bounds__(256, 4) void l1_kernel(
    const int* __restrict__ word_ids, const float* __restrict__ embed,
    const unsigned short* __restrict__ Bg, const float* __restrict__ bias,
    unsigned short* __restrict__ h1)
{
    __shared__ char smem[2048 + 2048];       // 32 node rows | 2 splitK slots
    const int tid = threadIdx.x, lane = tid & 63;
    const int l15 = lane & 15, hi = lane >> 4, wave = tid >> 6;
    const int n = wave >> 1, u = wave & 1;
    const int tile = blockIdx.x;

    // stage 32 leaf rows (bf16, swizzled). 256 thr x 8B.
    {
        int rr = tid >> 3, q4 = tid & 7;
        int r = rr >> 1, child = rr & 1;
        int g1 = tile * 16 + r;
        int leaf = (g1 >> 5) * 64 + (g1 & 31) * 2 + child;
        int wid = word_ids[leaf];
        float4 v = ((const float4*)(embed + (size_t)wid * 32))[q4];
        uint2 st;
        st.x = (unsigned)f2bf(v.x) | ((unsigned)f2bf(v.y) << 16);
        st.y = (unsigned)f2bf(v.z) | ((unsigned)f2bf(v.w) << 16);
        *(uint2*)(smem + node_addr(rr, q4 >> 1) + (q4 & 1) * 8) = st;
    }
    __syncthreads();

    float crot[64];
    load_crot(smem, 2 * l15, hi, crot);

    f32x4 acc = { 0.f, 0.f, 0.f, 0.f };
    if (u == 0) acc = run1_k<0, 34>(Bg, crot, lane, n, acc);
    else        acc = run1_k<34, 67>(Bg, crot, lane, n, acc);

    if (u == 1) *(f32x4*)(smem + 2048 + n * 1024 + lane * 16) = acc;
    __syncthreads();
    if (u == 0) {
        acc += *(const f32x4*)(smem + 2048 + n * 1024 + lane * 16);
        float bk = bias[n * 16 + l15];
        #pragma unroll
        for (int r = 0; r < 4; ++r) {
            int node = tile * 16 + hi * 4 + r;
            h1[(size_t)node * 32 + n * 16 + l15] = f2bf(tanhf(acc[r] + bk));
        }
    }
}

// ---------------------------------------------------------------------------
// Deep level helper (L3..L6): 2 trees/block, 1 tile (rows packed across trees),
// 8 waves = splitN2 x splitK4. RPT = out rows per tree.
// ---------------------------------------------------------------------------
constexpr int SCR = 8192;   // scratch base in tail smem

template<int RPT, int CHILDB, int OUTB, int OG, bool ROOT>
static __device__ __forceinline__ void level_deep(
    char* smem, const unsigned short* __restrict__ Bg,
    const float* __restrict__ bias, unsigned short* __restrict__ hbuf,
    float* __restrict__ roots, int bid, int lane, int wave)
{
    const int l15 = lane & 15, hi = lane >> 4;
    const int n = wave >> 2, u = wave & 3;

    int rc = (l15 < 2 * RPT) ? l15 : 0;
    int tree = rc / RPT, i = rc % RPT;
    float crot[64];
    load_crot(smem, tree * 64 + CHILDB + 2 * i, hi, crot);

    f32x4 acc = { 0.f, 0.f, 0.f, 0.f };
    switch (u) {
        case 0:  acc = run1_k< 0, 17>(Bg, crot, lane, n, acc); break;
        case 1:  acc = run1_k<17, 34>(Bg, crot, lane, n, acc); break;
        case 2:  acc = run1_k<34, 50>(Bg, crot, lane, n, acc); break;
        default: acc = run1_k<50, 67>(Bg, crot, lane, n, acc); break;
    }
    if (u > 0) *(f32x4*)(smem + SCR + (n * 3 + u - 1) * 1024 + lane * 16) = acc;
    __syncthreads();
    if (u == 0) {
        #pragma unroll
        for (int v2 = 0; v2 < 3; ++v2)
            acc += *(const f32x4*)(smem + SCR + (n * 3 + v2) * 1024 + lane * 16);
        float bk = bias[n * 16 + l15];
        int col = n * 16 + l15;
        #pragma unroll
        for (int r4 = 0; r4 < 4; ++r4) {
            int row = hi * 4 + r4;
            if (row < 2 * RPT) {
                float h = tanhf(acc[r4] + bk);
                unsigned short hb = f2bf(h);
                int t2 = row / RPT, i2 = row % RPT;
                *(unsigned short*)(smem + node_addr(t2 * 64 + OUTB + i2, col >> 3) + (col & 7) * 2) = hb;
                hbuf[((size_t)OG + (size_t)(bid * 2 + t2) * RPT + i2) * 32 + col] = hb;
                if (ROOT) roots[(size_t)(bid * 2 + t2) * 32 + col] = h;
            }
        }
    }
    __syncthreads();
}

// ---------------------------------------------------------------------------
// Tail kernel: levels 2..6. Block = 2 trees, 256 blocks (1/CU), 8 waves.
// LDS per tree (stride 64 rows): h1 in rows 0..31, L2 32..47, L3 48..55,
// L4 56..59, L5 60..61, L6 62.
// ---------------------------------------------------------------------------
__global__ __launch_bounds__(512, 2) void tail_kernel(
    const unsigned short* __restrict__ Bg, const float* __restrict__ bias,
    unsigned short* __restrict__ hbuf, float* __restrict__ roots)
{
    __shared__ char smem[8192 + 6144];       // 2x64 node rows | 6 splitK slots
    const int tid = threadIdx.x, lane = tid & 63;
    const int l15 = lane & 15, hi = lane >> 4, wave = tid >> 6;
    const int bid = blockIdx.x;

    // stage 2 trees' h1 (4 KB) coalesced: 256 x 16B chunks
    if (tid < 256) {
        int nr = tid >> 2, q = tid & 3;
        int t = nr >> 5, i = nr & 31;
        ushort8v v = *(const ushort8v*)(hbuf + ((size_t)(bid * 2 + t) * 32 + i) * 32 + q * 8);
        *(ushort8v*)(smem + node_addr(t * 64 + i, q)) = v;
    }
    __syncthreads();

    // ---- L2: per-tree tile, splitN2 x splitK2 ------------------------------
    {
        const int t = wave >> 2, n = (wave >> 1) & 1, u = wave & 1;
        float crot[64];
        load_crot(smem, t * 64 + 2 * l15, hi, crot);
        f32x4 acc = { 0.f, 0.f, 0.f, 0.f };
        if (u == 0) acc = run1_k<0, 34>(Bg, crot, lane, n, acc);
        else        acc = run1_k<34, 67>(Bg, crot, lane, n, acc);
        if (u == 1) *(f32x4*)(smem + SCR + (t * 2 + n) * 1024 + lane * 16) = acc;
        __syncthreads();
        if (u == 0) {
            acc += *(const f32x4*)(smem + SCR + (t * 2 + n) * 1024 + lane * 16);
            float bk = bias[n * 16 + l15];
            int col = n * 16 + l15;
            #pragma unroll
            for (int r4 = 0; r4 < 4; ++r4) {
                int row = hi * 4 + r4;
                float h = tanhf(acc[r4] + bk);
                unsigned short hb = f2bf(h);
                *(unsigned short*)(smem + node_addr(t * 64 + 32 + row, col >> 3) + (col & 7) * 2) = hb;
                hbuf[((size_t)16384 + (size_t)(bid * 2 + t) * 16 + row) * 32 + col] = hb;
            }
        }
        __syncthreads();
    }

    // ---- L3..L6 ------------------------------------------------------------
    level_deep<8, 32, 48, 24576, false>(smem, Bg, bias, hbuf, roots, bid, lane, wave);
    level_deep<4, 48, 56, 28672, false>(smem, Bg, bias, hbuf, roots, bid, lane, wave);
    level_deep<2, 56, 60, 30720, false>(smem, Bg, bias, hbuf, roots, bid, lane, wave);
    level_deep<1, 60, 62, 31744, true >(smem, Bg, bias, hbuf, roots, bid, lane, wave);
}

// ---------------------------------------------------------------------------
// out: logits + log_softmax. Leaves straight from fp32 embed (exact).
// ---------------------------------------------------------------------------
__global__ __launch_bounds__(256) void out_kernel(
    const int* __restrict__ word_ids, const float* __restrict__ embed,
    const unsigned short* __restrict__ hbuf,
    const float* __restrict__ Wout_w, const float* __restrict__ Wout_b,
    float* __restrict__ out)
{
    int g = blockIdx.x * 256 + threadIdx.x;
    if (g >= TOTAL_NODES) return;

    float h[32];
    if (g < NLEAF) {
        int wid = word_ids[g];
        const float4* p = (const float4*)(embed + (size_t)wid * 32);
        #pragma unroll
        for (int q = 0; q < 8; ++q) {
            float4 v = p[q];
            h[q*4] = v.x; h[q*4+1] = v.y; h[q*4+2] = v.z; h[q*4+3] = v.w;
        }
    } else {
        const ushort8v* p = (const ushort8v*)(hbuf + (size_t)(g - NLEAF) * 32);
        #pragma unroll
        for (int q = 0; q < 4; ++q) {
            ushort8v v = p[q];
            #pragma unroll
            for (int e = 0; e < 8; ++e) h[q*8+e] = bf2f(v[e]);
        }
    }

    float logits[OUT_N];
    #pragma unroll
    for (int o = 0; o < OUT_N; ++o) {
        const float* w = Wout_w + o * 32;
        float s = 0.f;
        #pragma unroll
        for (int x = 0; x < 32; ++x) s = fmaf(w[x], h[x], s);
        logits[o] = s + Wout_b[o];
    }
    float m = logits[0];
    #pragma unroll
    for (int o = 1; o < OUT_N; ++o) m = fmaxf(m, logits[o]);
    float sum = 0.f;
    #pragma unroll
    for (int o = 0; o < OUT_N; ++o) sum += expf(logits[o] - m);
    float lse = m + logf(sum);
    #pragma unroll
    for (int o = 0; o < OUT_N; ++o) out[(size_t)g * OUT_N + o] = logits[o] - lse;
}

// ---------------------------------------------------------------------------
extern "C" void kernel_launch(void* const* d_in, const int* in_sizes, int n_in,
                              void* d_out, int out_size, void* d_ws, size_t ws_size,
                              hipStream_t stream)
{
    const int*   word_ids = (const int*)  d_in[0];
    const float* embed    = (const float*)d_in[1];
    const float* V        = (const float*)d_in[2];
    const float* W        = (const float*)d_in[3];
    const float* bvec     = (const float*)d_in[4];
    const float* Wout_w   = (const float*)d_in[5];
    const float* Wout_b   = (const float*)d_in[6];
    float* out = (float*)d_out;

    // ws: Bfrag [137216 B] | hbuf 32256 nodes x 32 bf16 [2,064,384 B]
    unsigned short* Bfrag = (unsigned short*)d_ws;
    unsigned short* hbuf  = (unsigned short*)((char*)d_ws + 137216);
    float* roots = out + ROOTS_OFF;

    bprep_kernel<<<134, 64, 0, stream>>>(V, W, Bfrag);
    l1_kernel<<<1024, 256, 0, stream>>>(word_ids, embed, Bfrag, bvec, hbuf);
    tail_kernel<<<256, 512, 0, stream>>>(Bfrag, bvec, hbuf, roots);
    out_kernel<<<254, 256, 0, stream>>>(word_ids, embed, hbuf, Wout_w, Wout_b, out);
}